// Round 1
// baseline (656.983 us; speedup 1.0000x reference)
//
#include <hip/hip_runtime.h>
#include <hip/hip_bf16.h>

// Shapes (fixed by the reference)
#define BB   128
#define DDIM 256
#define HH   4
#define NNN  256
#define MMM  256
#define DHEAD 64   // DDIM/HH

typedef __hip_bfloat16 bf16;

__device__ __forceinline__ float ldconv(const float* p) { return *p; }
__device__ __forceinline__ float ldconv(const bf16* p)  { return __bfloat162float(*p); }

// ---------------------------------------------------------------------------
// Projection: Y[b,e,n] = sum_f W[e,f] * X[b,f,n] + bias[e]
// Tile 64(e) x 64(n), K-step 32, 256 threads, 4x4 register blocking.
// f-accumulation is strictly sequential f32 FMA (selection-path precision).
// ---------------------------------------------------------------------------
template <typename TIN, typename TOUT>
__global__ __launch_bounds__(256)
void proj_kernel(const TIN* __restrict__ X, const float* __restrict__ W,
                 const float* __restrict__ bias, TOUT* __restrict__ Y) {
    __shared__ float Wt[32][68];   // [f_local][e_local]
    __shared__ float Xt[32][68];   // [f_local][n_local]

    const int t  = threadIdx.x;
    const int tx = t & 15;         // n sub-tile
    const int ty = t >> 4;         // e sub-tile
    const int n0 = blockIdx.x * 64;
    const int e0 = blockIdx.y * 64;
    const int b  = blockIdx.z;
    const size_t plane = (size_t)b * DDIM * NNN;

    float acc[4][4] = {};

    for (int f0 = 0; f0 < DDIM; f0 += 32) {
        // stage W tile (transposed into [f][e])
        #pragma unroll
        for (int i = 0; i < 8; ++i) {
            int idx = t + i * 256;          // 0..2047
            int fl = idx & 31, el = idx >> 5;
            Wt[fl][el] = W[(size_t)(e0 + el) * DDIM + f0 + fl];
        }
        // stage X tile [f][n]
        #pragma unroll
        for (int i = 0; i < 8; ++i) {
            int idx = t + i * 256;
            int nl = idx & 63, fl = idx >> 6;
            Xt[fl][nl] = ldconv(&X[plane + (size_t)(f0 + fl) * NNN + n0 + nl]);
        }
        __syncthreads();

        #pragma unroll
        for (int ff = 0; ff < 32; ++ff) {
            const float4 av = *(const float4*)&Wt[ff][ty * 4];
            const float4 bv = *(const float4*)&Xt[ff][tx * 4];
            const float a[4] = {av.x, av.y, av.z, av.w};
            const float c[4] = {bv.x, bv.y, bv.z, bv.w};
            #pragma unroll
            for (int i = 0; i < 4; ++i)
                #pragma unroll
                for (int j = 0; j < 4; ++j)
                    acc[i][j] = fmaf(a[i], c[j], acc[i][j]);
        }
        __syncthreads();
    }

    #pragma unroll
    for (int i = 0; i < 4; ++i) {
        const int e = e0 + ty * 4 + i;
        const float bs = bias[e];
        const size_t off = plane + (size_t)e * NNN + n0 + tx * 4;
        if constexpr (sizeof(TOUT) == 4) {
            float4 o;
            o.x = acc[i][0] + bs; o.y = acc[i][1] + bs;
            o.z = acc[i][2] + bs; o.w = acc[i][3] + bs;
            *(float4*)&Y[off] = o;
        } else {
            bf16 tmp[4];
            tmp[0] = __float2bfloat16(acc[i][0] + bs);
            tmp[1] = __float2bfloat16(acc[i][1] + bs);
            tmp[2] = __float2bfloat16(acc[i][2] + bs);
            tmp[3] = __float2bfloat16(acc[i][3] + bs);
            *(uint2*)&Y[off] = *(const uint2*)tmp;
        }
    }
}

// ---------------------------------------------------------------------------
// Attention: per block = (b, h, 32-row n-tile).
//   scores[n][m] = sum_d q[d,n]*k[d,m] / 8   (f32, exact path)
//   per-row: k-th-largest threshold (with multiplicity), masked softmax
//   out[d][n] = sum_m prob[n][m] * v[d][m]
// ---------------------------------------------------------------------------
__global__ __launch_bounds__(256)
void attn_kernel(const float* __restrict__ qf, const float* __restrict__ kf,
                 const bf16* __restrict__ vf, bf16* __restrict__ ob,
                 const int* __restrict__ kptr) {
    __shared__ float s_s[32][260];   // scores -> probs (pad 260: 16B-aligned rows, banks spread)
    __shared__ float s_q[64][33];    // q[d][n_local]
    __shared__ float s_kv[2304];     // union: K view [64][36], V view [32][68]

    const int t  = threadIdx.x;
    const int n0 = blockIdx.x * 32;
    const int h  = blockIdx.y;
    const int b  = blockIdx.z;
    const size_t plane = (size_t)b * DDIM * NNN;

    // ---- stage Q tile: q[d][nl] = qf[b, d*H+h, n0+nl]
    #pragma unroll
    for (int i = 0; i < 8; ++i) {
        int idx = t + i * 256;
        int nl = idx & 31, d = idx >> 5;
        s_q[d][nl] = qf[plane + (size_t)(d * HH + h) * NNN + n0 + nl];
    }

    const int nn = t & 31;           // row within tile
    const int mb = (t >> 5) * 4;     // 4-wide m strip

    // ---- scores
    for (int m0 = 0; m0 < MMM; m0 += 32) {
        __syncthreads();             // protect s_kv reuse across iterations
        #pragma unroll
        for (int i = 0; i < 8; ++i) {
            int idx = t + i * 256;
            int ml = idx & 31, d = idx >> 5;
            s_kv[d * 36 + ml] = kf[plane + (size_t)(d * HH + h) * MMM + m0 + ml];
        }
        __syncthreads();

        float a0 = 0.f, a1 = 0.f, a2 = 0.f, a3 = 0.f;
        #pragma unroll
        for (int d = 0; d < 64; ++d) {
            const float qv = s_q[d][nn];
            const float4 kv = *(const float4*)&s_kv[d * 36 + mb];
            a0 = fmaf(qv, kv.x, a0);
            a1 = fmaf(qv, kv.y, a1);
            a2 = fmaf(qv, kv.z, a2);
            a3 = fmaf(qv, kv.w, a3);
        }
        *(float4*)&s_s[nn][m0 + mb] =
            make_float4(a0 * 0.125f, a1 * 0.125f, a2 * 0.125f, a3 * 0.125f);
    }
    __syncthreads();

    // ---- top-k threshold + masked softmax, one row per wave (4 waves x 8 rows)
    const int lane = t & 63;
    const int wv   = t >> 6;
    int kk = *kptr;
    if (kk < 1) kk = 1;
    if (kk > MMM) kk = MMM;

    #pragma unroll 1
    for (int r = wv * 8; r < wv * 8 + 8; ++r) {
        const float4 ov = *(const float4*)&s_s[r][lane * 4];  // pristine copy
        float w0 = ov.x, w1 = ov.y, w2 = ov.z, w3 = ov.w;     // working copy
        float rowmax = 0.f, thresh = 0.f;

        for (int it = 0; ; ++it) {
            float lm = fmaxf(fmaxf(w0, w1), fmaxf(w2, w3));
            float gm = lm;
            #pragma unroll
            for (int off = 1; off < 64; off <<= 1)
                gm = fmaxf(gm, __shfl_xor(gm, off, 64));
            if (it == 0) rowmax = gm;
            thresh = gm;
            if (it == kk - 1) break;
            // remove exactly one instance of the current max (multiplicity-exact)
            unsigned long long bal = __ballot(lm == gm);
            int leader = __ffsll((unsigned long long)bal) - 1;
            if (lane == leader) {
                if      (w0 == gm) w0 = -INFINITY;
                else if (w1 == gm) w1 = -INFINITY;
                else if (w2 == gm) w2 = -INFINITY;
                else               w3 = -INFINITY;
            }
        }

        float e0 = (ov.x >= thresh) ? expf(ov.x - rowmax) : 0.f;
        float e1 = (ov.y >= thresh) ? expf(ov.y - rowmax) : 0.f;
        float e2 = (ov.z >= thresh) ? expf(ov.z - rowmax) : 0.f;
        float e3 = (ov.w >= thresh) ? expf(ov.w - rowmax) : 0.f;
        float sm = e0 + e1 + e2 + e3;
        #pragma unroll
        for (int off = 1; off < 64; off <<= 1)
            sm += __shfl_xor(sm, off, 64);
        const float inv = 1.0f / sm;
        *(float4*)&s_s[r][lane * 4] = make_float4(e0 * inv, e1 * inv, e2 * inv, e3 * inv);
    }

    // ---- PV: out[d][n] = sum_m prob[n][m] * v[d][m]
    const int db = (t >> 5) * 8;     // 8-wide d strip
    float acc[8] = {};
    for (int m0 = 0; m0 < MMM; m0 += 32) {
        __syncthreads();             // protect s_kv (V view) reuse
        #pragma unroll
        for (int i = 0; i < 8; ++i) {
            int idx = t + i * 256;
            int ml = idx & 31, d = idx >> 5;
            s_kv[ml * 68 + d] =
                __bfloat162float(vf[plane + (size_t)(d * HH + h) * MMM + m0 + ml]);
        }
        __syncthreads();

        #pragma unroll
        for (int ml = 0; ml < 32; ++ml) {
            const float p = s_s[nn][m0 + ml];
            const float4 v0 = *(const float4*)&s_kv[ml * 68 + db];
            const float4 v1 = *(const float4*)&s_kv[ml * 68 + db + 4];
            acc[0] = fmaf(p, v0.x, acc[0]);
            acc[1] = fmaf(p, v0.y, acc[1]);
            acc[2] = fmaf(p, v0.z, acc[2]);
            acc[3] = fmaf(p, v0.w, acc[3]);
            acc[4] = fmaf(p, v1.x, acc[4]);
            acc[5] = fmaf(p, v1.y, acc[5]);
            acc[6] = fmaf(p, v1.z, acc[6]);
            acc[7] = fmaf(p, v1.w, acc[7]);
        }
    }

    #pragma unroll
    for (int j = 0; j < 8; ++j) {
        ob[plane + (size_t)((db + j) * HH + h) * NNN + n0 + nn] = __float2bfloat16(acc[j]);
    }
}

// ---------------------------------------------------------------------------
// Launch: qf(f32) kf(f32) vb(bf16) ob(bf16) in d_ws  (needs 100,663,296 B)
// ---------------------------------------------------------------------------
extern "C" void kernel_launch(void* const* d_in, const int* in_sizes, int n_in,
                              void* d_out, int out_size, void* d_ws, size_t ws_size,
                              hipStream_t stream) {
    const float* x   = (const float*)d_in[0];
    const float* src = (const float*)d_in[1];
    const float* Wq  = (const float*)d_in[2];
    const float* bq  = (const float*)d_in[3];
    const float* Wk  = (const float*)d_in[4];
    const float* bk  = (const float*)d_in[5];
    const float* Wv  = (const float*)d_in[6];
    const float* bv  = (const float*)d_in[7];
    const float* Wm  = (const float*)d_in[8];
    const float* bm  = (const float*)d_in[9];
    const int*   kp  = (const int*)d_in[10];
    float* out = (float*)d_out;

    const size_t F32PLANE = (size_t)BB * DDIM * NNN * sizeof(float);  // 33,554,432
    const size_t BF16PLANE = F32PLANE / 2;                            // 16,777,216
    char* ws = (char*)d_ws;
    float* qf = (float*)(ws);
    float* kf = (float*)(ws + F32PLANE);
    bf16*  vb = (bf16*)(ws + 2 * F32PLANE);
    bf16*  ob = (bf16*)(ws + 2 * F32PLANE + BF16PLANE);

    dim3 pgrid(NNN / 64, DDIM / 64, BB);   // (4,4,128)
    dim3 blk(256);
    hipLaunchKernelGGL((proj_kernel<float, float>), pgrid, blk, 0, stream, x,   Wq, bq, qf);
    hipLaunchKernelGGL((proj_kernel<float, float>), pgrid, blk, 0, stream, src, Wk, bk, kf);
    hipLaunchKernelGGL((proj_kernel<float, bf16 >), pgrid, blk, 0, stream, src, Wv, bv, vb);

    dim3 agrid(NNN / 32, HH, BB);          // (8,4,128)
    hipLaunchKernelGGL(attn_kernel, agrid, blk, 0, stream, qf, kf, vb, ob, kp);

    hipLaunchKernelGGL((proj_kernel<bf16, float>), pgrid, blk, 0, stream, ob, Wm, bm, out);
}

// Round 3
// 450.442 us; speedup vs baseline: 1.4585x; 1.4585x over previous
//
#include <hip/hip_runtime.h>
#include <hip/hip_bf16.h>

#define BB   128
#define DDIM 256
#define HH   4
#define NNN  256
#define MMM  256

typedef __hip_bfloat16 bf16;
typedef short  short8   __attribute__((ext_vector_type(8)));
typedef unsigned short ushort8_t __attribute__((ext_vector_type(8)));
typedef float  f32x4    __attribute__((ext_vector_type(4)));

// LDS map (dynamic, 73728 B):
//   phase 1 (stage+QK^T):
//     0     .. 16384 : Q hi  [128 n][64 d] bf16, row 128 B
//     16384 .. 32768 : Q mid
//     32768 .. 49152 : Q lo
//     49152 .. 57344 : K hi  [64 m][64 d] bf16 (per 64-m tile)
//     57344 .. 65536 : K mid
//     65536 .. 73728 : K lo
//   phase 2 (softmax+PV):  (Q frags already in registers, K consumed)
//     0     .. 32768 : P [64 rows][256 m] bf16 (one nf-half per pass)
//     32768 .. 65536 : V [64 d][256 m] bf16
//   phase 3 (output):
//     0     .. 16384 : out [64 d][128 n] bf16
// all tiles: byte = row*STRIDE + (colbytes ^ ((row&7)<<4))

// ---------------- helpers ----------------
__device__ __forceinline__ unsigned short f2bf(float x) {       // RNE f32->bf16
    unsigned u = __builtin_bit_cast(unsigned, x);
    u += 0x7FFFu + ((u >> 16) & 1u);
    return (unsigned short)(u >> 16);
}
__device__ __forceinline__ float bf2f(unsigned short b) {
    unsigned u = ((unsigned)b) << 16;
    return __builtin_bit_cast(float, u);
}

// transpose a 4x4 f32 tile held across 4 consecutive lanes (p = lane&3).
// in: v[c] = M[p][c]   out: v[c] = M[c][p]
__device__ __forceinline__ void xpose4(float v[4], const int p) {
    float ta = __shfl_xor((p & 1) ? v[0] : v[1], 1, 64);
    float tb = __shfl_xor((p & 1) ? v[2] : v[3], 1, 64);
    float u0 = (p & 1) ? ta : v[0];
    float u1 = (p & 1) ? v[1] : ta;
    float u2 = (p & 1) ? tb : v[2];
    float u3 = (p & 1) ? v[3] : tb;
    float tc = __shfl_xor((p & 2) ? u0 : u2, 2, 64);
    float td = __shfl_xor((p & 2) ? u1 : u3, 2, 64);
    v[0] = (p & 2) ? tc : u0;
    v[1] = (p & 2) ? td : u1;
    v[2] = (p & 2) ? u2 : tc;
    v[3] = (p & 2) ? u3 : td;
}

// 3-level bf16 split: v = hi + mid + lo + O(2^-27 v)
__device__ __forceinline__ void split3_pack_store(char* dh, char* dm, char* dl,
                                                  const float v[4]) {
    unsigned short h[4], m[4], l[4];
    #pragma unroll
    for (int i = 0; i < 4; ++i) {
        h[i] = f2bf(v[i]);
        float r1 = v[i] - bf2f(h[i]);
        m[i] = f2bf(r1);
        float r2 = r1 - bf2f(m[i]);
        l[i] = f2bf(r2);
    }
    uint2 hp, mp, lp;
    hp.x = (unsigned)h[0] | ((unsigned)h[1] << 16);
    hp.y = (unsigned)h[2] | ((unsigned)h[3] << 16);
    mp.x = (unsigned)m[0] | ((unsigned)m[1] << 16);
    mp.y = (unsigned)m[2] | ((unsigned)m[3] << 16);
    lp.x = (unsigned)l[0] | ((unsigned)l[1] << 16);
    lp.y = (unsigned)l[2] | ((unsigned)l[3] << 16);
    *(uint2*)dh = hp;
    *(uint2*)dm = mp;
    *(uint2*)dl = lp;
}

__device__ __forceinline__ float max16v(const float* w) {
    float a = fmaxf(fmaxf(w[0], w[1]),  fmaxf(w[2], w[3]));
    float b = fmaxf(fmaxf(w[4], w[5]),  fmaxf(w[6], w[7]));
    float c = fmaxf(fmaxf(w[8], w[9]),  fmaxf(w[10], w[11]));
    float d = fmaxf(fmaxf(w[12], w[13]), fmaxf(w[14], w[15]));
    return fmaxf(fmaxf(a, b), fmaxf(c, d));
}
__device__ __forceinline__ float gmax16(float v) {              // max over 16-lane group
    v = fmaxf(v, __shfl_xor(v, 1, 64));
    v = fmaxf(v, __shfl_xor(v, 2, 64));
    v = fmaxf(v, __shfl_xor(v, 4, 64));
    v = fmaxf(v, __shfl_xor(v, 8, 64));
    return v;
}
__device__ __forceinline__ float gsum16(float v) {
    v += __shfl_xor(v, 1, 64);
    v += __shfl_xor(v, 2, 64);
    v += __shfl_xor(v, 4, 64);
    v += __shfl_xor(v, 8, 64);
    return v;
}

template <int NF>
__device__ __forceinline__ void softmax_half(f32x4 (&acc)[2][16], const float (&thr)[2][4],
                                             const float (&rmx)[2][4], char* smem,
                                             int w, int lane, int g, int c16) {
    #pragma unroll
    for (int mf = 0; mf < 16; ++mf) {
        #pragma unroll
        for (int r = 0; r < 4; ++r) {
            float a = acc[NF][mf][r];
            acc[NF][mf][r] = (a >= thr[NF][r]) ? __expf(a - rmx[NF][r]) : 0.f;
        }
    }
    float inv_[4];
    #pragma unroll
    for (int r = 0; r < 4; ++r) {
        float s = ((acc[NF][0][r] + acc[NF][1][r]) + (acc[NF][2][r] + acc[NF][3][r]))
                + ((acc[NF][4][r] + acc[NF][5][r]) + (acc[NF][6][r] + acc[NF][7][r]))
                + ((acc[NF][8][r] + acc[NF][9][r]) + (acc[NF][10][r] + acc[NF][11][r]))
                + ((acc[NF][12][r] + acc[NF][13][r]) + (acc[NF][14][r] + acc[NF][15][r]));
        s = gsum16(s);
        inv_[r] = 1.0f / s;
    }
    #pragma unroll
    for (int mf = 0; mf < 16; ++mf) {
        #pragma unroll
        for (int r = 0; r < 4; ++r) {
            int row = w * 16 + g * 4 + r;
            int m2  = (mf * 16 + c16) * 2;
            int off = row * 512 + (m2 ^ ((row & 7) << 4));   // P at base 0
            *(unsigned short*)(smem + off) = f2bf(acc[NF][mf][r] * inv_[r]);
        }
    }
}

template <int NF>
__device__ __forceinline__ void pv_half(f32x4 (&o)[2][4], const char* smem,
                                        int w, int lane, int c16) {
    short8 pa[8];
    #pragma unroll
    for (int ks = 0; ks < 8; ++ks) {
        int row = w * 16 + c16;
        int off = row * 512 + ((ks * 64 + (lane >> 4) * 16) ^ ((row & 7) << 4));
        pa[ks] = *(const short8*)(smem + off);
    }
    #pragma unroll
    for (int df = 0; df < 4; ++df) {
        f32x4 o_ = {0.f, 0.f, 0.f, 0.f};
        #pragma unroll
        for (int ks = 0; ks < 8; ++ks) {
            int d = df * 16 + c16;
            int off = 32768 + d * 512 + ((ks * 64 + (lane >> 4) * 16) ^ ((d & 7) << 4));
            short8 vv = *(const short8*)(smem + off);
            o_ = __builtin_amdgcn_mfma_f32_16x16x32_bf16(pa[ks], vv, o_, 0, 0, 0);
        }
        o[NF][df] = o_;
    }
}

// ---------------------------------------------------------------------------
// Fused attention, MFMA, 3-term bf16-split f32-accurate scores.
// Block = (b, h, 128-row n-tile). 256 threads.
// ---------------------------------------------------------------------------
__global__ __launch_bounds__(256, 2)
void attn2_kernel(const float* __restrict__ qf, const float* __restrict__ kf,
                  const bf16* __restrict__ vb, bf16* __restrict__ ob,
                  const int* __restrict__ kptr) {
    extern __shared__ __align__(16) char smem[];

    const int t    = threadIdx.x;
    const int lane = t & 63;
    const int w    = t >> 6;
    const int g    = lane >> 4;
    const int c16  = lane & 15;

    // XCD-chunked swizzle: sibling n-tiles of one (b,h) share an XCD L2
    const int i    = blockIdx.x;
    const int work = (i & 7) * 128 + (i >> 3);
    const int bx = work & 1;
    const int h  = (work >> 1) & 3;
    const int b  = work >> 3;
    const int n0 = bx * 128;

    const size_t planeF = (size_t)b * DDIM * NNN;
    const size_t planeV = (size_t)b * DDIM * MMM;

    int kk = kptr[0];
    kk = kk < 1 ? 1 : (kk > MMM ? MMM : kk);

    // ---- Phase 0: stage Q (x0.125, 3-way split, transpose -> [n][d]) ----
    {
        const int p = lane & 3, G = lane >> 2;
        #pragma unroll
        for (int it = 0; it < 8; ++it) {
            int chunk = w + 4 * it;                 // 0..31
            int dch = chunk & 15, nh = chunk >> 4;
            int drow = dch * 4 + p;
            int ncol = n0 + nh * 64 + G * 4;
            float v[4];
            const float4 f4 = *(const float4*)&qf[planeF + (size_t)(drow * HH + h) * NNN + ncol];
            v[0] = f4.x * 0.125f; v[1] = f4.y * 0.125f;
            v[2] = f4.z * 0.125f; v[3] = f4.w * 0.125f;
            xpose4(v, p);
            int nl = nh * 64 + G * 4 + p;           // block-local n
            int base = nl * 128 + ((dch * 8) ^ ((nl & 7) << 4));
            split3_pack_store(smem + base, smem + 16384 + base, smem + 32768 + base, v);
        }
    }
    __syncthreads();

    // ---- A-fragments (Q) -> registers, kept for whole kernel ----
    short8 qh[2][2], qm[2][2], ql[2][2];
    #pragma unroll
    for (int nf = 0; nf < 2; ++nf) {
        #pragma unroll
        for (int ks = 0; ks < 2; ++ks) {
            int nl = w * 32 + nf * 16 + c16;
            int off = nl * 128 + ((ks * 64 + (lane >> 4) * 16) ^ ((nl & 7) << 4));
            qh[nf][ks] = *(const short8*)(smem + off);
            qm[nf][ks] = *(const short8*)(smem + 16384 + off);
            ql[nf][ks] = *(const short8*)(smem + 32768 + off);
        }
    }

    // ---- scores ----
    f32x4 acc[2][16];
    #pragma unroll
    for (int a = 0; a < 2; ++a)
        #pragma unroll
        for (int m = 0; m < 16; ++m)
            acc[a][m] = f32x4{0.f, 0.f, 0.f, 0.f};

    #pragma unroll 1
    for (int tt = 0; tt < 4; ++tt) {
        // stage K tile [64 m][64 d], 3-way split
        {
            const int p = lane & 3, G = lane >> 2;
            #pragma unroll
            for (int it = 0; it < 4; ++it) {
                int chunk = w + 4 * it;             // 0..15
                int drow = chunk * 4 + p;
                int mcol = tt * 64 + G * 4;
                float v[4];
                const float4 f4 = *(const float4*)&kf[planeF + (size_t)(drow * HH + h) * MMM + mcol];
                v[0] = f4.x; v[1] = f4.y; v[2] = f4.z; v[3] = f4.w;
                xpose4(v, p);
                int ml = G * 4 + p;                 // tile-local m
                int base = ml * 128 + ((chunk * 8) ^ ((ml & 7) << 4));
                split3_pack_store(smem + 49152 + base, smem + 57344 + base,
                                  smem + 65536 + base, v);
            }
        }
        __syncthreads();
        #pragma unroll
        for (int mf = 0; mf < 4; ++mf) {
            #pragma unroll
            for (int ks = 0; ks < 2; ++ks) {
                int ml = mf * 16 + c16;
                int off = ml * 128 + ((ks * 64 + (lane >> 4) * 16) ^ ((ml & 7) << 4));
                short8 bh = *(const short8*)(smem + 49152 + off);
                short8 bm = *(const short8*)(smem + 57344 + off);
                short8 bl = *(const short8*)(smem + 65536 + off);
                #pragma unroll
                for (int nf = 0; nf < 2; ++nf) {
                    f32x4 a = acc[nf][tt * 4 + mf];
                    a = __builtin_amdgcn_mfma_f32_16x16x32_bf16(qh[nf][ks], bh, a, 0, 0, 0);
                    a = __builtin_amdgcn_mfma_f32_16x16x32_bf16(qh[nf][ks], bm, a, 0, 0, 0);
                    a = __builtin_amdgcn_mfma_f32_16x16x32_bf16(qm[nf][ks], bh, a, 0, 0, 0);
                    a = __builtin_amdgcn_mfma_f32_16x16x32_bf16(qm[nf][ks], bm, a, 0, 0, 0);
                    a = __builtin_amdgcn_mfma_f32_16x16x32_bf16(qh[nf][ks], bl, a, 0, 0, 0);
                    a = __builtin_amdgcn_mfma_f32_16x16x32_bf16(ql[nf][ks], bh, a, 0, 0, 0);
                    acc[nf][tt * 4 + mf] = a;
                }
            }
        }
        __syncthreads();
    }

    // ---- kick off V loads (global -> regs), hide latency under top-k ----
    ushort8_t vreg[8];
    #pragma unroll
    for (int it = 0; it < 8; ++it) {
        int idx = t + it * 256;                     // 0..2047
        int d = idx >> 5, mc = idx & 31;
        vreg[it] = *(const ushort8_t*)&vb[planeV + (size_t)(d * HH + h) * MMM + mc * 8];
    }

    // ---- top-k thresholds (exact, multiplicity-aware) ----
    float thr[2][4], rmx[2][4];
    #pragma unroll
    for (int nf = 0; nf < 2; ++nf) {
        #pragma unroll
        for (int r = 0; r < 4; ++r) {
            float w16[16];
            #pragma unroll
            for (int mf = 0; mf < 16; ++mf) w16[mf] = acc[nf][mf][r];
            float lm = max16v(w16);
            float gm = gmax16(lm);
            rmx[nf][r] = gm;
            for (int it = 1; it < kk; ++it) {
                unsigned long long bal = __ballot(lm == gm);
                unsigned gmask = (unsigned)((bal >> (g * 16)) & 0xFFFFull);
                int leader = __builtin_ctz(gmask);
                bool skip = (c16 != leader);
                #pragma unroll
                for (int mf = 0; mf < 16; ++mf) {
                    bool hit = (!skip) && (w16[mf] == gm);
                    w16[mf] = hit ? -INFINITY : w16[mf];
                    skip = skip || hit;
                }
                lm = max16v(w16);
                gm = gmax16(lm);
            }
            thr[nf][r] = gm;
        }
    }

    // ---- softmax + P write (half 0), V -> LDS ----
    softmax_half<0>(acc, thr, rmx, smem, w, lane, g, c16);
    #pragma unroll
    for (int it = 0; it < 8; ++it) {
        int idx = t + it * 256;
        int d = idx >> 5, mc = idx & 31;
        int off = 32768 + d * 512 + ((mc * 16) ^ ((d & 7) << 4));
        *(ushort8_t*)(smem + off) = vreg[it];
    }
    __syncthreads();

    f32x4 o[2][4];
    pv_half<0>(o, smem, w, lane, c16);
    __syncthreads();
    softmax_half<1>(acc, thr, rmx, smem, w, lane, g, c16);
    __syncthreads();
    pv_half<1>(o, smem, w, lane, c16);
    __syncthreads();                                 // P region becomes out region

    // ---- out: frags -> s_out [64 d][128 n] (base 0) -> global ----
    #pragma unroll
    for (int nf = 0; nf < 2; ++nf)
        #pragma unroll
        for (int df = 0; df < 4; ++df)
            #pragma unroll
            for (int r = 0; r < 4; ++r) {
                int d  = df * 16 + c16;
                int nl = w * 32 + nf * 16 + g * 4 + r;
                int off = d * 256 + ((nl * 2) ^ ((d & 7) << 4));
                *(unsigned short*)(smem + off) = f2bf(o[nf][df][r]);
            }
    __syncthreads();
    #pragma unroll
    for (int it = 0; it < 4; ++it) {
        int idx = t + it * 256;                     // 0..1023
        int d = idx >> 4, ch = idx & 15;
        int off = d * 256 + ((ch * 16) ^ ((d & 7) << 4));
        ushort8_t val = *(const ushort8_t*)(smem + off);
        *(ushort8_t*)&ob[planeV + (size_t)(d * HH + h) * NNN + n0 + ch * 8] = val;
    }
}

// ---------------------------------------------------------------------------
// Projection (identical to round 1): Y[b,e,n] = sum_f W[e,f] X[b,f,n] + b[e]
// ---------------------------------------------------------------------------
__device__ __forceinline__ float ldconv(const float* p) { return *p; }
__device__ __forceinline__ float ldconv(const bf16* p)  { return __bfloat162float(*p); }

template <typename TIN, typename TOUT>
__global__ __launch_bounds__(256)
void proj_kernel(const TIN* __restrict__ X, const float* __restrict__ W,
                 const float* __restrict__ bias, TOUT* __restrict__ Y) {
    __shared__ float Wt[32][68];
    __shared__ float Xt[32][68];

    const int t  = threadIdx.x;
    const int tx = t & 15;
    const int ty = t >> 4;
    const int n0 = blockIdx.x * 64;
    const int e0 = blockIdx.y * 64;
    const int b  = blockIdx.z;
    const size_t plane = (size_t)b * DDIM * NNN;

    float acc[4][4] = {};

    for (int f0 = 0; f0 < DDIM; f0 += 32) {
        #pragma unroll
        for (int i = 0; i < 8; ++i) {
            int idx = t + i * 256;
            int fl = idx & 31, el = idx >> 5;
            Wt[fl][el] = W[(size_t)(e0 + el) * DDIM + f0 + fl];
        }
        #pragma unroll
        for (int i = 0; i < 8; ++i) {
            int idx = t + i * 256;
            int nl = idx & 63, fl = idx >> 6;
            Xt[fl][nl] = ldconv(&X[plane + (size_t)(f0 + fl) * NNN + n0 + nl]);
        }
        __syncthreads();

        #pragma unroll
        for (int ff = 0; ff < 32; ++ff) {
            const float4 av = *(const float4*)&Wt[ff][ty * 4];
            const float4 bv = *(const float4*)&Xt[ff][tx * 4];
            const float a[4] = {av.x, av.y, av.z, av.w};
            const float c[4] = {bv.x, bv.y, bv.z, bv.w};
            #pragma unroll
            for (int i2 = 0; i2 < 4; ++i2)
                #pragma unroll
                for (int j = 0; j < 4; ++j)
                    acc[i2][j] = fmaf(a[i2], c[j], acc[i2][j]);
        }
        __syncthreads();
    }

    #pragma unroll
    for (int i2 = 0; i2 < 4; ++i2) {
        const int e = e0 + ty * 4 + i2;
        const float bs = bias[e];
        const size_t off = plane + (size_t)e * NNN + n0 + tx * 4;
        if constexpr (sizeof(TOUT) == 4) {
            float4 o;
            o.x = acc[i2][0] + bs; o.y = acc[i2][1] + bs;
            o.z = acc[i2][2] + bs; o.w = acc[i2][3] + bs;
            *(float4*)&Y[off] = o;
        } else {
            bf16 tmp[4];
            tmp[0] = __float2bfloat16(acc[i2][0] + bs);
            tmp[1] = __float2bfloat16(acc[i2][1] + bs);
            tmp[2] = __float2bfloat16(acc[i2][2] + bs);
            tmp[3] = __float2bfloat16(acc[i2][3] + bs);
            *(uint2*)&Y[off] = *(const uint2*)tmp;
        }
    }
}

// ---------------------------------------------------------------------------
extern "C" void kernel_launch(void* const* d_in, const int* in_sizes, int n_in,
                              void* d_out, int out_size, void* d_ws, size_t ws_size,
                              hipStream_t stream) {
    const float* x   = (const float*)d_in[0];
    const float* src = (const float*)d_in[1];
    const float* Wq  = (const float*)d_in[2];
    const float* bq  = (const float*)d_in[3];
    const float* Wk  = (const float*)d_in[4];
    const float* bk  = (const float*)d_in[5];
    const float* Wv  = (const float*)d_in[6];
    const float* bv  = (const float*)d_in[7];
    const float* Wm  = (const float*)d_in[8];
    const float* bm  = (const float*)d_in[9];
    const int*   kp  = (const int*)d_in[10];
    float* out = (float*)d_out;

    const size_t F32PLANE  = (size_t)BB * DDIM * NNN * sizeof(float);
    const size_t BF16PLANE = F32PLANE / 2;
    char* ws = (char*)d_ws;
    float* qf = (float*)(ws);
    float* kf = (float*)(ws + F32PLANE);
    bf16*  vb = (bf16*)(ws + 2 * F32PLANE);
    bf16*  ob = (bf16*)(ws + 2 * F32PLANE + BF16PLANE);

    dim3 pgrid(NNN / 64, DDIM / 64, BB);
    dim3 blk(256);
    hipLaunchKernelGGL((proj_kernel<float, float>), pgrid, blk, 0, stream, x,   Wq, bq, qf);
    hipLaunchKernelGGL((proj_kernel<float, float>), pgrid, blk, 0, stream, src, Wk, bk, kf);
    hipLaunchKernelGGL((proj_kernel<float, bf16 >), pgrid, blk, 0, stream, src, Wv, bv, vb);

    hipFuncSetAttribute((const void*)attn2_kernel,
                        hipFuncAttributeMaxDynamicSharedMemorySize, 73728);
    hipLaunchKernelGGL(attn2_kernel, dim3(1024), blk, 73728, stream, qf, kf, vb, ob, kp);

    hipLaunchKernelGGL((proj_kernel<bf16, float>), pgrid, blk, 0, stream, ob, Wm, bm, out);
}

// Round 5
// 290.047 us; speedup vs baseline: 2.2651x; 1.5530x over previous
//
#include <hip/hip_runtime.h>
#include <hip/hip_bf16.h>

#define BB   128
#define DDIM 256
#define HH   4
#define NNN  256
#define MMM  256

typedef __hip_bfloat16 bf16;
typedef short  short8   __attribute__((ext_vector_type(8)));
typedef unsigned short ushort8_t __attribute__((ext_vector_type(8)));
typedef float  f32x4    __attribute__((ext_vector_type(4)));

// ---------------- helpers ----------------
__device__ __forceinline__ unsigned short f2bf(float x) {       // RNE f32->bf16
    unsigned u = __builtin_bit_cast(unsigned, x);
    u += 0x7FFFu + ((u >> 16) & 1u);
    return (unsigned short)(u >> 16);
}
__device__ __forceinline__ float bf2f(unsigned short b) {
    unsigned u = ((unsigned)b) << 16;
    return __builtin_bit_cast(float, u);
}

// transpose a 4x4 f32 tile held across 4 consecutive lanes (p = lane&3).
__device__ __forceinline__ void xpose4(float v[4], const int p) {
    float ta = __shfl_xor((p & 1) ? v[0] : v[1], 1, 64);
    float tb = __shfl_xor((p & 1) ? v[2] : v[3], 1, 64);
    float u0 = (p & 1) ? ta : v[0];
    float u1 = (p & 1) ? v[1] : ta;
    float u2 = (p & 1) ? tb : v[2];
    float u3 = (p & 1) ? v[3] : tb;
    float tc = __shfl_xor((p & 2) ? u0 : u2, 2, 64);
    float td = __shfl_xor((p & 2) ? u1 : u3, 2, 64);
    v[0] = (p & 2) ? tc : u0;
    v[1] = (p & 2) ? td : u1;
    v[2] = (p & 2) ? u2 : tc;
    v[3] = (p & 2) ? u3 : td;
}

// 3-level bf16 split: v = hi + mid + lo + O(2^-27 v)
__device__ __forceinline__ void split3_pack_store(char* dh, char* dm, char* dl,
                                                  const float v[4]) {
    unsigned short h[4], m[4], l[4];
    #pragma unroll
    for (int i = 0; i < 4; ++i) {
        h[i] = f2bf(v[i]);
        float r1 = v[i] - bf2f(h[i]);
        m[i] = f2bf(r1);
        float r2 = r1 - bf2f(m[i]);
        l[i] = f2bf(r2);
    }
    uint2 hp, mp, lp;
    hp.x = (unsigned)h[0] | ((unsigned)h[1] << 16);
    hp.y = (unsigned)h[2] | ((unsigned)h[3] << 16);
    mp.x = (unsigned)m[0] | ((unsigned)m[1] << 16);
    mp.y = (unsigned)m[2] | ((unsigned)m[3] << 16);
    lp.x = (unsigned)l[0] | ((unsigned)l[1] << 16);
    lp.y = (unsigned)l[2] | ((unsigned)l[3] << 16);
    *(uint2*)dh = hp;
    *(uint2*)dm = mp;
    *(uint2*)dl = lp;
}

// 2-plane split (planes 16384 B apart): hi/mid
__device__ __forceinline__ void split2_store(char* dst, const float v[4]) {
    unsigned short h[4], m[4];
    #pragma unroll
    for (int i = 0; i < 4; ++i) {
        h[i] = f2bf(v[i]);
        float r1 = v[i] - bf2f(h[i]);
        m[i] = f2bf(r1);
    }
    uint2 hp, mp;
    hp.x = (unsigned)h[0] | ((unsigned)h[1] << 16);
    hp.y = (unsigned)h[2] | ((unsigned)h[3] << 16);
    mp.x = (unsigned)m[0] | ((unsigned)m[1] << 16);
    mp.y = (unsigned)m[2] | ((unsigned)m[3] << 16);
    *(uint2*)dst = hp;
    *(uint2*)(dst + 16384) = mp;
}

__device__ __forceinline__ void ldx4(const float* p, float v[4]) {
    const float4 f = *(const float4*)p;
    v[0] = f.x; v[1] = f.y; v[2] = f.z; v[3] = f.w;
}
__device__ __forceinline__ void ldx4(const bf16* p, float v[4]) {
    uint2 u = *(const uint2*)p;
    v[0] = bf2f((unsigned short)(u.x & 0xFFFF));
    v[1] = bf2f((unsigned short)(u.x >> 16));
    v[2] = bf2f((unsigned short)(u.y & 0xFFFF));
    v[3] = bf2f((unsigned short)(u.y >> 16));
}

__device__ __forceinline__ float max16v(const float* w) {
    float a = fmaxf(fmaxf(w[0], w[1]),  fmaxf(w[2], w[3]));
    float b = fmaxf(fmaxf(w[4], w[5]),  fmaxf(w[6], w[7]));
    float c = fmaxf(fmaxf(w[8], w[9]),  fmaxf(w[10], w[11]));
    float d = fmaxf(fmaxf(w[12], w[13]), fmaxf(w[14], w[15]));
    return fmaxf(fmaxf(a, b), fmaxf(c, d));
}
__device__ __forceinline__ float gmax16(float v) {
    v = fmaxf(v, __shfl_xor(v, 1, 64));
    v = fmaxf(v, __shfl_xor(v, 2, 64));
    v = fmaxf(v, __shfl_xor(v, 4, 64));
    v = fmaxf(v, __shfl_xor(v, 8, 64));
    return v;
}
__device__ __forceinline__ float gsum16(float v) {
    v += __shfl_xor(v, 1, 64);
    v += __shfl_xor(v, 2, 64);
    v += __shfl_xor(v, 4, 64);
    v += __shfl_xor(v, 8, 64);
    return v;
}

// ---------------------------------------------------------------------------
// MFMA projection (VALUE-LEVEL paths only: V and output).
// 512 threads, tile 128e x 128n, f-step 64. 2-term split, combos hh,hm,mh.
// LDS 64 KB: X planes [128n][64f] at 0/16384; W planes [128e][64f] at 32768/49152.
// ---------------------------------------------------------------------------
template <typename TIN, typename TOUT>
__global__ __launch_bounds__(512, 2)
void projm_kernel(const TIN* __restrict__ X, const float* __restrict__ W,
                  const float* __restrict__ bias, TOUT* __restrict__ Y) {
    extern __shared__ __align__(16) char smem[];

    const int t    = threadIdx.x;
    const int lane = t & 63;
    const int w    = t >> 6;          // 0..7
    const int c16  = lane & 15;
    const int g    = (lane >> 4) & 3;
    const int p    = lane & 3;
    const int G    = lane >> 2;       // 0..15

    const int n0 = blockIdx.x * 128;
    const int e0 = blockIdx.y * 128;
    const int b  = blockIdx.z;
    const size_t plane = (size_t)b * DDIM * NNN;

    f32x4 acc[8];
    #pragma unroll
    for (int nf = 0; nf < 8; ++nf) acc[nf] = f32x4{0.f, 0.f, 0.f, 0.f};

    #pragma unroll
    for (int ft = 0; ft < 4; ++ft) {
        const int f0 = ft * 64;
        if (ft) __syncthreads();
        // ---- stage X chunk [64f x 128n] -> transposed [128n][64f], 2 planes
        #pragma unroll
        for (int it = 0; it < 4; ++it) {
            int chunk = w + 8 * it;            // 0..31
            int fch = chunk & 15, nh = chunk >> 4;
            float v[4];
            ldx4(&X[plane + (size_t)(f0 + fch * 4 + p) * NNN + n0 + nh * 64 + G * 4], v);
            xpose4(v, p);
            int nl = nh * 64 + G * 4 + p;
            int base = nl * 128 + ((fch * 8) ^ ((nl & 7) << 4));
            split2_store(smem + base, v);
        }
        // ---- stage W chunk [128e x 64f] (no transpose), 2 planes
        #pragma unroll
        for (int it = 0; it < 4; ++it) {
            int idx = t + 512 * it;            // 0..2047
            int el = idx >> 4, fq = idx & 15;
            float v[4];
            const float4 f4 = *(const float4*)&W[(size_t)(e0 + el) * DDIM + f0 + fq * 4];
            v[0] = f4.x; v[1] = f4.y; v[2] = f4.z; v[3] = f4.w;
            int base = 32768 + el * 128 + ((fq * 8) ^ ((el & 7) << 4));
            split2_store(smem + base, v);
        }
        __syncthreads();

        // ---- MFMA: wave w owns e-rows [w*16, w*16+16)
        const int ew = w * 16;
        short8 a0[2], a1[2];
        #pragma unroll
        for (int ks = 0; ks < 2; ++ks) {
            int off = 32768 + (ew + c16) * 128
                    + ((ks * 64 + g * 16) ^ ((c16 & 7) << 4));
            a0[ks] = *(const short8*)(smem + off);
            a1[ks] = *(const short8*)(smem + off + 16384);
        }
        #pragma unroll
        for (int nf = 0; nf < 8; ++nf) {
            #pragma unroll
            for (int ks = 0; ks < 2; ++ks) {
                int off = (nf * 16 + c16) * 128
                        + ((ks * 64 + g * 16) ^ ((c16 & 7) << 4));
                short8 b0 = *(const short8*)(smem + off);
                short8 b1 = *(const short8*)(smem + off + 16384);
                f32x4 a = acc[nf];
                a = __builtin_amdgcn_mfma_f32_16x16x32_bf16(a0[ks], b0, a, 0, 0, 0);
                a = __builtin_amdgcn_mfma_f32_16x16x32_bf16(a0[ks], b1, a, 0, 0, 0);
                a = __builtin_amdgcn_mfma_f32_16x16x32_bf16(a1[ks], b0, a, 0, 0, 0);
                acc[nf] = a;
            }
        }
    }

    // ---- epilogue: C row = e (g*4+r), col = n (c16)
    const int ew = w * 16;
    float bs[4];
    #pragma unroll
    for (int r = 0; r < 4; ++r) bs[r] = bias[e0 + ew + g * 4 + r];
    #pragma unroll
    for (int nf = 0; nf < 8; ++nf) {
        #pragma unroll
        for (int r = 0; r < 4; ++r) {
            size_t off = plane + (size_t)(e0 + ew + g * 4 + r) * NNN + n0 + nf * 16 + c16;
            float val = acc[nf][r] + bs[r];
            if constexpr (sizeof(TOUT) == 4) Y[off] = val;
            else                             *(unsigned short*)&Y[off] = f2bf(val);
        }
    }
}

// ---------------------------------------------------------------------------
// f32 projection (round-1, known-good): SELECTION paths (Q, K).
// ---------------------------------------------------------------------------
template <typename TIN, typename TOUT>
__global__ __launch_bounds__(256)
void proj_kernel(const TIN* __restrict__ X, const float* __restrict__ W,
                 const float* __restrict__ bias, TOUT* __restrict__ Y) {
    __shared__ float Wt[32][68];
    __shared__ float Xt[32][68];

    const int t  = threadIdx.x;
    const int tx = t & 15;
    const int ty = t >> 4;
    const int n0 = blockIdx.x * 64;
    const int e0 = blockIdx.y * 64;
    const int b  = blockIdx.z;
    const size_t plane = (size_t)b * DDIM * NNN;

    float acc[4][4] = {};

    for (int f0 = 0; f0 < DDIM; f0 += 32) {
        #pragma unroll
        for (int i = 0; i < 8; ++i) {
            int idx = t + i * 256;
            int fl = idx & 31, el = idx >> 5;
            Wt[fl][el] = W[(size_t)(e0 + el) * DDIM + f0 + fl];
        }
        #pragma unroll
        for (int i = 0; i < 8; ++i) {
            int idx = t + i * 256;
            int nl = idx & 63, fl = idx >> 6;
            Xt[fl][nl] = X[plane + (size_t)(f0 + fl) * NNN + n0 + nl];
        }
        __syncthreads();

        #pragma unroll
        for (int ff = 0; ff < 32; ++ff) {
            const float4 av = *(const float4*)&Wt[ff][ty * 4];
            const float4 bv = *(const float4*)&Xt[ff][tx * 4];
            const float a[4] = {av.x, av.y, av.z, av.w};
            const float c[4] = {bv.x, bv.y, bv.z, bv.w};
            #pragma unroll
            for (int i2 = 0; i2 < 4; ++i2)
                #pragma unroll
                for (int j = 0; j < 4; ++j)
                    acc[i2][j] = fmaf(a[i2], c[j], acc[i2][j]);
        }
        __syncthreads();
    }

    #pragma unroll
    for (int i2 = 0; i2 < 4; ++i2) {
        const int e = e0 + ty * 4 + i2;
        const float bs = bias[e];
        const size_t off = plane + (size_t)e * NNN + n0 + tx * 4;
        float4 o;
        o.x = acc[i2][0] + bs; o.y = acc[i2][1] + bs;
        o.z = acc[i2][2] + bs; o.w = acc[i2][3] + bs;
        *(float4*)&Y[off] = o;
    }
}

// ---------------------------------------------------------------------------
// Fused attention (round-4 full-unroll version, unchanged).
// ---------------------------------------------------------------------------
template <int NF>
__device__ __forceinline__ void softmax_half(f32x4 (&acc)[2][16], const float (&thr)[2][4],
                                             const float (&rmx)[2][4], char* smem,
                                             int w, int lane, int g, int c16) {
    #pragma unroll
    for (int mf = 0; mf < 16; ++mf) {
        #pragma unroll
        for (int r = 0; r < 4; ++r) {
            float a = acc[NF][mf][r];
            acc[NF][mf][r] = (a >= thr[NF][r]) ? __expf(a - rmx[NF][r]) : 0.f;
        }
    }
    float inv_[4];
    #pragma unroll
    for (int r = 0; r < 4; ++r) {
        float s = ((acc[NF][0][r] + acc[NF][1][r]) + (acc[NF][2][r] + acc[NF][3][r]))
                + ((acc[NF][4][r] + acc[NF][5][r]) + (acc[NF][6][r] + acc[NF][7][r]))
                + ((acc[NF][8][r] + acc[NF][9][r]) + (acc[NF][10][r] + acc[NF][11][r]))
                + ((acc[NF][12][r] + acc[NF][13][r]) + (acc[NF][14][r] + acc[NF][15][r]));
        s = gsum16(s);
        inv_[r] = 1.0f / s;
    }
    #pragma unroll
    for (int mf = 0; mf < 16; ++mf) {
        #pragma unroll
        for (int r = 0; r < 4; ++r) {
            int row = w * 16 + g * 4 + r;
            int m2  = (mf * 16 + c16) * 2;
            int off = row * 512 + (m2 ^ ((row & 7) << 4));
            *(unsigned short*)(smem + off) = f2bf(acc[NF][mf][r] * inv_[r]);
        }
    }
}

template <int NF>
__device__ __forceinline__ void pv_half(f32x4 (&o)[2][4], const char* smem,
                                        int w, int lane, int c16) {
    short8 pa[8];
    #pragma unroll
    for (int ks = 0; ks < 8; ++ks) {
        int row = w * 16 + c16;
        int off = row * 512 + ((ks * 64 + (lane >> 4) * 16) ^ ((row & 7) << 4));
        pa[ks] = *(const short8*)(smem + off);
    }
    #pragma unroll
    for (int df = 0; df < 4; ++df) {
        f32x4 o_ = {0.f, 0.f, 0.f, 0.f};
        #pragma unroll
        for (int ks = 0; ks < 8; ++ks) {
            int d = df * 16 + c16;
            int off = 32768 + d * 512 + ((ks * 64 + (lane >> 4) * 16) ^ ((d & 7) << 4));
            short8 vv = *(const short8*)(smem + off);
            o_ = __builtin_amdgcn_mfma_f32_16x16x32_bf16(pa[ks], vv, o_, 0, 0, 0);
        }
        o[NF][df] = o_;
    }
}

__global__ __launch_bounds__(256, 2)
void attn2_kernel(const float* __restrict__ qf, const float* __restrict__ kf,
                  const bf16* __restrict__ vb, bf16* __restrict__ ob,
                  const int* __restrict__ kptr) {
    extern __shared__ __align__(16) char smem[];

    const int t    = threadIdx.x;
    const int lane = t & 63;
    const int w    = t >> 6;
    const int g    = lane >> 4;
    const int c16  = lane & 15;

    const int i    = blockIdx.x;
    const int work = (i & 7) * 128 + (i >> 3);
    const int bx = work & 1;
    const int h  = (work >> 1) & 3;
    const int b  = work >> 3;
    const int n0 = bx * 128;

    const size_t planeF = (size_t)b * DDIM * NNN;
    const size_t planeV = (size_t)b * DDIM * MMM;

    int kk = kptr[0];
    kk = kk < 1 ? 1 : (kk > MMM ? MMM : kk);

    // ---- Phase 0: stage Q (x0.125, 3-way split, transpose -> [n][d]) ----
    {
        const int p = lane & 3, G = lane >> 2;
        #pragma unroll
        for (int it = 0; it < 8; ++it) {
            int chunk = w + 4 * it;
            int dch = chunk & 15, nh = chunk >> 4;
            int drow = dch * 4 + p;
            int ncol = n0 + nh * 64 + G * 4;
            float v[4];
            const float4 f4 = *(const float4*)&qf[planeF + (size_t)(drow * HH + h) * NNN + ncol];
            v[0] = f4.x * 0.125f; v[1] = f4.y * 0.125f;
            v[2] = f4.z * 0.125f; v[3] = f4.w * 0.125f;
            xpose4(v, p);
            int nl = nh * 64 + G * 4 + p;
            int base = nl * 128 + ((dch * 8) ^ ((nl & 7) << 4));
            split3_pack_store(smem + base, smem + 16384 + base, smem + 32768 + base, v);
        }
    }
    __syncthreads();

    short8 qh[2][2], qm[2][2], ql[2][2];
    #pragma unroll
    for (int nf = 0; nf < 2; ++nf) {
        #pragma unroll
        for (int ks = 0; ks < 2; ++ks) {
            int nl = w * 32 + nf * 16 + c16;
            int off = nl * 128 + ((ks * 64 + (lane >> 4) * 16) ^ ((nl & 7) << 4));
            qh[nf][ks] = *(const short8*)(smem + off);
            qm[nf][ks] = *(const short8*)(smem + 16384 + off);
            ql[nf][ks] = *(const short8*)(smem + 32768 + off);
        }
    }

    f32x4 acc[2][16];
    #pragma unroll
    for (int a = 0; a < 2; ++a)
        #pragma unroll
        for (int m = 0; m < 16; ++m)
            acc[a][m] = f32x4{0.f, 0.f, 0.f, 0.f};

    #pragma unroll
    for (int tt = 0; tt < 4; ++tt) {        // full unroll: static acc indices
        {
            const int p = lane & 3, G = lane >> 2;
            #pragma unroll
            for (int it = 0; it < 4; ++it) {
                int chunk = w + 4 * it;
                int drow = chunk * 4 + p;
                int mcol = tt * 64 + G * 4;
                float v[4];
                const float4 f4 = *(const float4*)&kf[planeF + (size_t)(drow * HH + h) * MMM + mcol];
                v[0] = f4.x; v[1] = f4.y; v[2] = f4.z; v[3] = f4.w;
                xpose4(v, p);
                int ml = G * 4 + p;
                int base = ml * 128 + ((chunk * 8) ^ ((ml & 7) << 4));
                split3_pack_store(smem + 49152 + base, smem + 57344 + base,
                                  smem + 65536 + base, v);
            }
        }
        __syncthreads();
        #pragma unroll
        for (int mf = 0; mf < 4; ++mf) {
            #pragma unroll
            for (int ks = 0; ks < 2; ++ks) {
                int ml = mf * 16 + c16;
                int off = ml * 128 + ((ks * 64 + (lane >> 4) * 16) ^ ((ml & 7) << 4));
                short8 bh = *(const short8*)(smem + 49152 + off);
                short8 bm = *(const short8*)(smem + 57344 + off);
                short8 bl = *(const short8*)(smem + 65536 + off);
                #pragma unroll
                for (int nf = 0; nf < 2; ++nf) {
                    f32x4 a = acc[nf][tt * 4 + mf];
                    a = __builtin_amdgcn_mfma_f32_16x16x32_bf16(qh[nf][ks], bh, a, 0, 0, 0);
                    a = __builtin_amdgcn_mfma_f32_16x16x32_bf16(qh[nf][ks], bm, a, 0, 0, 0);
                    a = __builtin_amdgcn_mfma_f32_16x16x32_bf16(qm[nf][ks], bh, a, 0, 0, 0);
                    a = __builtin_amdgcn_mfma_f32_16x16x32_bf16(qm[nf][ks], bm, a, 0, 0, 0);
                    a = __builtin_amdgcn_mfma_f32_16x16x32_bf16(qh[nf][ks], bl, a, 0, 0, 0);
                    a = __builtin_amdgcn_mfma_f32_16x16x32_bf16(ql[nf][ks], bh, a, 0, 0, 0);
                    acc[nf][tt * 4 + mf] = a;
                }
            }
        }
        __syncthreads();
    }

    ushort8_t vreg[8];
    #pragma unroll
    for (int it = 0; it < 8; ++it) {
        int idx = t + it * 256;
        int d = idx >> 5, mc = idx & 31;
        vreg[it] = *(const ushort8_t*)&vb[planeV + (size_t)(d * HH + h) * MMM + mc * 8];
    }

    float thr[2][4], rmx[2][4];
    #pragma unroll
    for (int nf = 0; nf < 2; ++nf) {
        #pragma unroll
        for (int r = 0; r < 4; ++r) {
            float w16[16];
            #pragma unroll
            for (int mf = 0; mf < 16; ++mf) w16[mf] = acc[nf][mf][r];
            float lm = max16v(w16);
            float gm = gmax16(lm);
            rmx[nf][r] = gm;
            for (int it = 1; it < kk; ++it) {
                unsigned long long bal = __ballot(lm == gm);
                unsigned gmask = (unsigned)((bal >> (g * 16)) & 0xFFFFull);
                int leader = __builtin_ctz(gmask);
                bool skip = (c16 != leader);
                #pragma unroll
                for (int mf = 0; mf < 16; ++mf) {
                    bool hit = (!skip) && (w16[mf] == gm);
                    w16[mf] = hit ? -INFINITY : w16[mf];
                    skip = skip || hit;
                }
                lm = max16v(w16);
                gm = gmax16(lm);
            }
            thr[nf][r] = gm;
        }
    }

    softmax_half<0>(acc, thr, rmx, smem, w, lane, g, c16);
    #pragma unroll
    for (int it = 0; it < 8; ++it) {
        int idx = t + it * 256;
        int d = idx >> 5, mc = idx & 31;
        int off = 32768 + d * 512 + ((mc * 16) ^ ((d & 7) << 4));
        *(ushort8_t*)(smem + off) = vreg[it];
    }
    __syncthreads();

    f32x4 o[2][4];
    pv_half<0>(o, smem, w, lane, c16);
    __syncthreads();
    softmax_half<1>(acc, thr, rmx, smem, w, lane, g, c16);
    __syncthreads();
    pv_half<1>(o, smem, w, lane, c16);
    __syncthreads();

    #pragma unroll
    for (int nf = 0; nf < 2; ++nf)
        #pragma unroll
        for (int df = 0; df < 4; ++df)
            #pragma unroll
            for (int r = 0; r < 4; ++r) {
                int d  = df * 16 + c16;
                int nl = w * 32 + nf * 16 + g * 4 + r;
                int off = d * 256 + ((nl * 2) ^ ((d & 7) << 4));
                *(unsigned short*)(smem + off) = f2bf(o[nf][df][r]);
            }
    __syncthreads();
    #pragma unroll
    for (int it = 0; it < 4; ++it) {
        int idx = t + it * 256;
        int d = idx >> 4, ch = idx & 15;
        int off = d * 256 + ((ch * 16) ^ ((d & 7) << 4));
        ushort8_t val = *(const ushort8_t*)(smem + off);
        *(ushort8_t*)&ob[planeV + (size_t)(d * HH + h) * NNN + n0 + ch * 8] = val;
    }
}

// ---------------------------------------------------------------------------
extern "C" void kernel_launch(void* const* d_in, const int* in_sizes, int n_in,
                              void* d_out, int out_size, void* d_ws, size_t ws_size,
                              hipStream_t stream) {
    const float* x   = (const float*)d_in[0];
    const float* src = (const float*)d_in[1];
    const float* Wq  = (const float*)d_in[2];
    const float* bq  = (const float*)d_in[3];
    const float* Wk  = (const float*)d_in[4];
    const float* bk  = (const float*)d_in[5];
    const float* Wv  = (const float*)d_in[6];
    const float* bv  = (const float*)d_in[7];
    const float* Wm  = (const float*)d_in[8];
    const float* bm  = (const float*)d_in[9];
    const int*   kp  = (const int*)d_in[10];
    float* out = (float*)d_out;

    const size_t F32PLANE  = (size_t)BB * DDIM * NNN * sizeof(float);
    const size_t BF16PLANE = F32PLANE / 2;
    char* ws = (char*)d_ws;
    float* qf = (float*)(ws);
    float* kf = (float*)(ws + F32PLANE);
    bf16*  vb = (bf16*)(ws + 2 * F32PLANE);
    bf16*  ob = (bf16*)(ws + 2 * F32PLANE + BF16PLANE);

    hipFuncSetAttribute((const void*)(projm_kernel<float, bf16>),
                        hipFuncAttributeMaxDynamicSharedMemorySize, 65536);
    hipFuncSetAttribute((const void*)(projm_kernel<bf16, float>),
                        hipFuncAttributeMaxDynamicSharedMemorySize, 65536);
    hipFuncSetAttribute((const void*)attn2_kernel,
                        hipFuncAttributeMaxDynamicSharedMemorySize, 73728);

    // Q, K: known-good f32 projection (selection path)
    dim3 fgrid(NNN / 64, DDIM / 64, BB);   // (4,4,128)
    hipLaunchKernelGGL((proj_kernel<float, float>), fgrid, dim3(256), 0, stream,
                       x,   Wq, bq, qf);
    hipLaunchKernelGGL((proj_kernel<float, float>), fgrid, dim3(256), 0, stream,
                       src, Wk, bk, kf);

    // V: MFMA projection (value path)
    dim3 mgrid(2, 2, BB);
    hipLaunchKernelGGL((projm_kernel<float, bf16>), mgrid, dim3(512), 65536, stream,
                       src, Wv, bv, vb);

    hipLaunchKernelGGL(attn2_kernel, dim3(1024), dim3(256), 73728, stream,
                       qf, kf, vb, ob, kp);

    // Output: MFMA projection (value path)
    hipLaunchKernelGGL((projm_kernel<bf16, float>), mgrid, dim3(512), 65536, stream,
                       ob, Wm, bm, out);
}

// Round 6
// 280.438 us; speedup vs baseline: 2.3427x; 1.0343x over previous
//
#include <hip/hip_runtime.h>
#include <hip/hip_bf16.h>

#define BB   128
#define DDIM 256
#define HH   4
#define NNN  256
#define MMM  256

typedef __hip_bfloat16 bf16;
typedef short  short8   __attribute__((ext_vector_type(8)));
typedef unsigned short ushort8_t __attribute__((ext_vector_type(8)));
typedef float  f32x4    __attribute__((ext_vector_type(4)));

// ---------------- helpers ----------------
__device__ __forceinline__ unsigned short f2bf(float x) {       // RNE f32->bf16
    unsigned u = __builtin_bit_cast(unsigned, x);
    u += 0x7FFFu + ((u >> 16) & 1u);
    return (unsigned short)(u >> 16);
}
__device__ __forceinline__ float bf2f(unsigned short b) {
    unsigned u = ((unsigned)b) << 16;
    return __builtin_bit_cast(float, u);
}

// transpose a 4x4 f32 tile held across 4 consecutive lanes (p = lane&3).
__device__ __forceinline__ void xpose4(float v[4], const int p) {
    float ta = __shfl_xor((p & 1) ? v[0] : v[1], 1, 64);
    float tb = __shfl_xor((p & 1) ? v[2] : v[3], 1, 64);
    float u0 = (p & 1) ? ta : v[0];
    float u1 = (p & 1) ? v[1] : ta;
    float u2 = (p & 1) ? tb : v[2];
    float u3 = (p & 1) ? v[3] : tb;
    float tc = __shfl_xor((p & 2) ? u0 : u2, 2, 64);
    float td = __shfl_xor((p & 2) ? u1 : u3, 2, 64);
    v[0] = (p & 2) ? tc : u0;
    v[1] = (p & 2) ? td : u1;
    v[2] = (p & 2) ? u2 : tc;
    v[3] = (p & 2) ? u3 : td;
}

// 3-level bf16 split to 3 planes 8192 B apart
__device__ __forceinline__ void split3_store8k(char* dst, const float v[4]) {
    unsigned short h[4], m[4], l[4];
    #pragma unroll
    for (int i = 0; i < 4; ++i) {
        h[i] = f2bf(v[i]);
        float r1 = v[i] - bf2f(h[i]);
        m[i] = f2bf(r1);
        float r2 = r1 - bf2f(m[i]);
        l[i] = f2bf(r2);
    }
    uint2 hp, mp, lp;
    hp.x = (unsigned)h[0] | ((unsigned)h[1] << 16);
    hp.y = (unsigned)h[2] | ((unsigned)h[3] << 16);
    mp.x = (unsigned)m[0] | ((unsigned)m[1] << 16);
    mp.y = (unsigned)m[2] | ((unsigned)m[3] << 16);
    lp.x = (unsigned)l[0] | ((unsigned)l[1] << 16);
    lp.y = (unsigned)l[2] | ((unsigned)l[3] << 16);
    *(uint2*)dst = hp;
    *(uint2*)(dst + 8192) = mp;
    *(uint2*)(dst + 16384) = lp;
}

// 2-plane split (planes 16384 B apart): hi/mid   (projm, value paths)
__device__ __forceinline__ void split2_store(char* dst, const float v[4]) {
    unsigned short h[4], m[4];
    #pragma unroll
    for (int i = 0; i < 4; ++i) {
        h[i] = f2bf(v[i]);
        float r1 = v[i] - bf2f(h[i]);
        m[i] = f2bf(r1);
    }
    uint2 hp, mp;
    hp.x = (unsigned)h[0] | ((unsigned)h[1] << 16);
    hp.y = (unsigned)h[2] | ((unsigned)h[3] << 16);
    mp.x = (unsigned)m[0] | ((unsigned)m[1] << 16);
    mp.y = (unsigned)m[2] | ((unsigned)m[3] << 16);
    *(uint2*)dst = hp;
    *(uint2*)(dst + 16384) = mp;
}

__device__ __forceinline__ void ldx4(const float* p, float v[4]) {
    const float4 f = *(const float4*)p;
    v[0] = f.x; v[1] = f.y; v[2] = f.z; v[3] = f.w;
}
__device__ __forceinline__ void ldx4(const bf16* p, float v[4]) {
    uint2 u = *(const uint2*)p;
    v[0] = bf2f((unsigned short)(u.x & 0xFFFF));
    v[1] = bf2f((unsigned short)(u.x >> 16));
    v[2] = bf2f((unsigned short)(u.y & 0xFFFF));
    v[3] = bf2f((unsigned short)(u.y >> 16));
}

__device__ __forceinline__ float max16v(const float* w) {
    float a = fmaxf(fmaxf(w[0], w[1]),  fmaxf(w[2], w[3]));
    float b = fmaxf(fmaxf(w[4], w[5]),  fmaxf(w[6], w[7]));
    float c = fmaxf(fmaxf(w[8], w[9]),  fmaxf(w[10], w[11]));
    float d = fmaxf(fmaxf(w[12], w[13]), fmaxf(w[14], w[15]));
    return fmaxf(fmaxf(a, b), fmaxf(c, d));
}
__device__ __forceinline__ float gmax16(float v) {
    v = fmaxf(v, __shfl_xor(v, 1, 64));
    v = fmaxf(v, __shfl_xor(v, 2, 64));
    v = fmaxf(v, __shfl_xor(v, 4, 64));
    v = fmaxf(v, __shfl_xor(v, 8, 64));
    return v;
}
__device__ __forceinline__ float gsum16(float v) {
    v += __shfl_xor(v, 1, 64);
    v += __shfl_xor(v, 2, 64);
    v += __shfl_xor(v, 4, 64);
    v += __shfl_xor(v, 8, 64);
    return v;
}

// ---------------------------------------------------------------------------
// f32 projection (SELECTION paths Q,K). Bit-identical accumulation to the
// verified round-1 kernel: per output element, sequential FMA over f=0..255.
// Tile 64e x 128n, 256 threads, 8e x 4n per thread.
// ---------------------------------------------------------------------------
__global__ __launch_bounds__(256)
void proj_kernel(const float* __restrict__ X, const float* __restrict__ W,
                 const float* __restrict__ bias, float* __restrict__ Y) {
    __shared__ float Wt[32][68];    // [f_local][e_local 0..63]
    __shared__ float Xt[32][132];   // [f_local][n_local 0..127]

    const int t  = threadIdx.x;
    const int tx = t & 31;          // n sub-tile: 4n at tx*4
    const int ty = t >> 5;          // e sub-tile: 8e at ty*8
    const int n0 = blockIdx.x * 128;
    const int e0 = blockIdx.y * 64;
    const int b  = blockIdx.z;
    const size_t plane = (size_t)b * DDIM * NNN;

    float acc[8][4] = {};

    for (int f0 = 0; f0 < DDIM; f0 += 32) {
        #pragma unroll
        for (int i = 0; i < 8; ++i) {
            int idx = t + i * 256;          // 0..2047
            int fl = idx & 31, el = idx >> 5;
            Wt[fl][el] = W[(size_t)(e0 + el) * DDIM + f0 + fl];
        }
        #pragma unroll
        for (int i = 0; i < 4; ++i) {
            int idx = t + i * 256;          // 0..1023
            int fl = idx >> 5, nl4 = idx & 31;
            *(float4*)&Xt[fl][nl4 * 4] =
                *(const float4*)&X[plane + (size_t)(f0 + fl) * NNN + n0 + nl4 * 4];
        }
        __syncthreads();

        #pragma unroll
        for (int ff = 0; ff < 32; ++ff) {
            const float4 av0 = *(const float4*)&Wt[ff][ty * 8];
            const float4 av1 = *(const float4*)&Wt[ff][ty * 8 + 4];
            const float4 bv  = *(const float4*)&Xt[ff][tx * 4];
            const float a[8] = {av0.x, av0.y, av0.z, av0.w, av1.x, av1.y, av1.z, av1.w};
            const float c[4] = {bv.x, bv.y, bv.z, bv.w};
            #pragma unroll
            for (int i2 = 0; i2 < 8; ++i2)
                #pragma unroll
                for (int j = 0; j < 4; ++j)
                    acc[i2][j] = fmaf(a[i2], c[j], acc[i2][j]);
        }
        __syncthreads();
    }

    #pragma unroll
    for (int i2 = 0; i2 < 8; ++i2) {
        const int e = e0 + ty * 8 + i2;
        const float bs = bias[e];
        const size_t off = plane + (size_t)e * NNN + n0 + tx * 4;
        float4 o;
        o.x = acc[i2][0] + bs; o.y = acc[i2][1] + bs;
        o.z = acc[i2][2] + bs; o.w = acc[i2][3] + bs;
        *(float4*)&Y[off] = o;
    }
}

// ---------------------------------------------------------------------------
// MFMA projection (VALUE paths: V, output). Unchanged from round 5 (verified).
// ---------------------------------------------------------------------------
template <typename TIN, typename TOUT>
__global__ __launch_bounds__(512, 2)
void projm_kernel(const TIN* __restrict__ X, const float* __restrict__ W,
                  const float* __restrict__ bias, TOUT* __restrict__ Y) {
    extern __shared__ __align__(16) char smem[];

    const int t    = threadIdx.x;
    const int lane = t & 63;
    const int w    = t >> 6;
    const int c16  = lane & 15;
    const int g    = (lane >> 4) & 3;
    const int p    = lane & 3;
    const int G    = lane >> 2;

    const int n0 = blockIdx.x * 128;
    const int e0 = blockIdx.y * 128;
    const int b  = blockIdx.z;
    const size_t plane = (size_t)b * DDIM * NNN;

    f32x4 acc[8];
    #pragma unroll
    for (int nf = 0; nf < 8; ++nf) acc[nf] = f32x4{0.f, 0.f, 0.f, 0.f};

    #pragma unroll
    for (int ft = 0; ft < 4; ++ft) {
        const int f0 = ft * 64;
        if (ft) __syncthreads();
        #pragma unroll
        for (int it = 0; it < 4; ++it) {
            int chunk = w + 8 * it;
            int fch = chunk & 15, nh = chunk >> 4;
            float v[4];
            ldx4(&X[plane + (size_t)(f0 + fch * 4 + p) * NNN + n0 + nh * 64 + G * 4], v);
            xpose4(v, p);
            int nl = nh * 64 + G * 4 + p;
            int base = nl * 128 + ((fch * 8) ^ ((nl & 7) << 4));
            split2_store(smem + base, v);
        }
        #pragma unroll
        for (int it = 0; it < 4; ++it) {
            int idx = t + 512 * it;
            int el = idx >> 4, fq = idx & 15;
            float v[4];
            const float4 f4 = *(const float4*)&W[(size_t)(e0 + el) * DDIM + f0 + fq * 4];
            v[0] = f4.x; v[1] = f4.y; v[2] = f4.z; v[3] = f4.w;
            int base = 32768 + el * 128 + ((fq * 8) ^ ((el & 7) << 4));
            split2_store(smem + base, v);
        }
        __syncthreads();

        const int ew = w * 16;
        short8 a0[2], a1[2];
        #pragma unroll
        for (int ks = 0; ks < 2; ++ks) {
            int off = 32768 + (ew + c16) * 128
                    + ((ks * 64 + g * 16) ^ ((c16 & 7) << 4));
            a0[ks] = *(const short8*)(smem + off);
            a1[ks] = *(const short8*)(smem + off + 16384);
        }
        #pragma unroll
        for (int nf = 0; nf < 8; ++nf) {
            #pragma unroll
            for (int ks = 0; ks < 2; ++ks) {
                int off = (nf * 16 + c16) * 128
                        + ((ks * 64 + g * 16) ^ ((c16 & 7) << 4));
                short8 b0 = *(const short8*)(smem + off);
                short8 b1 = *(const short8*)(smem + off + 16384);
                f32x4 a = acc[nf];
                a = __builtin_amdgcn_mfma_f32_16x16x32_bf16(a0[ks], b0, a, 0, 0, 0);
                a = __builtin_amdgcn_mfma_f32_16x16x32_bf16(a0[ks], b1, a, 0, 0, 0);
                a = __builtin_amdgcn_mfma_f32_16x16x32_bf16(a1[ks], b0, a, 0, 0, 0);
                acc[nf] = a;
            }
        }
    }

    const int ew = w * 16;
    float bs[4];
    #pragma unroll
    for (int r = 0; r < 4; ++r) bs[r] = bias[e0 + ew + g * 4 + r];
    #pragma unroll
    for (int nf = 0; nf < 8; ++nf) {
        #pragma unroll
        for (int r = 0; r < 4; ++r) {
            size_t off = plane + (size_t)(e0 + ew + g * 4 + r) * NNN + n0 + nf * 16 + c16;
            float val = acc[nf][r] + bs[r];
            if constexpr (sizeof(TOUT) == 4) Y[off] = val;
            else                             *(unsigned short*)&Y[off] = f2bf(val);
        }
    }
}

// ---------------------------------------------------------------------------
// attn3: 64-row n-tiles, 4 waves (16 rows/wave), acc[16] in VGPRs.
// LDS (dyn 49152):
//  phase1: Q [64n][64d] bf16 x3 planes @0/8192/16384; K [64m][64d] x3 @24576/32768/40960
//  phase2: P [64][256] bf16 @0 (32K); V-half [64d][128m] bf16 @32768 (16K)
//  phase3: out [64d][64n] bf16 @0 (8K)
// swizzle everywhere: byte = row*STRIDE + (colbytes ^ ((row&7)<<4))
// ---------------------------------------------------------------------------
__global__ __launch_bounds__(256, 3)
void attn3_kernel(const float* __restrict__ qf, const float* __restrict__ kf,
                  const bf16* __restrict__ vb, bf16* __restrict__ ob,
                  const int* __restrict__ kptr) {
    extern __shared__ __align__(16) char smem[];

    const int t    = threadIdx.x;
    const int lane = t & 63;
    const int w    = t >> 6;
    const int g    = lane >> 4;
    const int c16  = lane & 15;

    // XCD-chunked swizzle: 4 sibling n-tiles of one (b,h) stay on one XCD
    const int i    = blockIdx.x;
    const int work = (i & 7) * 256 + (i >> 3);
    const int bx = work & 3;
    const int h  = (work >> 2) & 3;
    const int b  = work >> 4;
    const int n0 = bx * 64;

    const size_t planeF = (size_t)b * DDIM * NNN;
    const size_t planeV = (size_t)b * DDIM * MMM;

    int kk = kptr[0];
    kk = kk < 1 ? 1 : (kk > MMM ? MMM : kk);

    // ---- stage Q (x0.125, 3-way split, transpose -> [64n][64d]) ----
    {
        const int p = lane & 3, G = lane >> 2;
        #pragma unroll
        for (int it = 0; it < 4; ++it) {
            int dch = w + 4 * it;               // 0..15
            int drow = dch * 4 + p;
            float v[4];
            const float4 f4 = *(const float4*)&qf[planeF + (size_t)(drow * HH + h) * NNN + n0 + G * 4];
            v[0] = f4.x * 0.125f; v[1] = f4.y * 0.125f;
            v[2] = f4.z * 0.125f; v[3] = f4.w * 0.125f;
            xpose4(v, p);
            int nl = G * 4 + p;                 // 0..63
            int base = nl * 128 + ((dch * 8) ^ ((nl & 7) << 4));
            split3_store8k(smem + base, v);
        }
    }
    __syncthreads();

    // ---- Q A-fragments: rows w*16+c16 ----
    short8 qh[2], qm[2], ql[2];
    #pragma unroll
    for (int ks = 0; ks < 2; ++ks) {
        int nl = w * 16 + c16;
        int off = nl * 128 + ((ks * 64 + g * 16) ^ ((nl & 7) << 4));
        qh[ks] = *(const short8*)(smem + off);
        qm[ks] = *(const short8*)(smem + 8192 + off);
        ql[ks] = *(const short8*)(smem + 16384 + off);
    }

    // ---- scores: acc[mf] covers m = mf*16 + c16 ----
    f32x4 acc[16];
    #pragma unroll
    for (int m = 0; m < 16; ++m) acc[m] = f32x4{0.f, 0.f, 0.f, 0.f};

    #pragma unroll
    for (int tt = 0; tt < 4; ++tt) {
        if (tt) __syncthreads();                // protect K region from prev readers
        {
            const int p = lane & 3, G = lane >> 2;
            #pragma unroll
            for (int it = 0; it < 4; ++it) {
                int dch = w + 4 * it;           // 0..15
                int drow = dch * 4 + p;
                int mcol = tt * 64 + G * 4;
                float v[4];
                const float4 f4 = *(const float4*)&kf[planeF + (size_t)(drow * HH + h) * MMM + mcol];
                v[0] = f4.x; v[1] = f4.y; v[2] = f4.z; v[3] = f4.w;
                xpose4(v, p);
                int ml = G * 4 + p;             // tile-local m 0..63
                int base = 24576 + ml * 128 + ((dch * 8) ^ ((ml & 7) << 4));
                split3_store8k(smem + base, v);
            }
        }
        __syncthreads();
        #pragma unroll
        for (int mf = 0; mf < 4; ++mf) {
            #pragma unroll
            for (int ks = 0; ks < 2; ++ks) {
                int ml = mf * 16 + c16;
                int off = 24576 + ml * 128 + ((ks * 64 + g * 16) ^ ((ml & 7) << 4));
                short8 bh = *(const short8*)(smem + off);
                short8 bm = *(const short8*)(smem + 8192 + off);
                short8 bl = *(const short8*)(smem + 16384 + off);
                f32x4 a = acc[tt * 4 + mf];
                a = __builtin_amdgcn_mfma_f32_16x16x32_bf16(qh[ks], bh, a, 0, 0, 0);
                a = __builtin_amdgcn_mfma_f32_16x16x32_bf16(qh[ks], bm, a, 0, 0, 0);
                a = __builtin_amdgcn_mfma_f32_16x16x32_bf16(qm[ks], bh, a, 0, 0, 0);
                a = __builtin_amdgcn_mfma_f32_16x16x32_bf16(qm[ks], bm, a, 0, 0, 0);
                a = __builtin_amdgcn_mfma_f32_16x16x32_bf16(qh[ks], bl, a, 0, 0, 0);
                a = __builtin_amdgcn_mfma_f32_16x16x32_bf16(ql[ks], bh, a, 0, 0, 0);
                acc[tt * 4 + mf] = a;
            }
        }
    }
    __syncthreads();        // all K reads done: P/V regions are free

    // ---- top-k thresholds (exact, multiplicity-aware); rows g*4+r ----
    float thr[4], rmx[4];
    #pragma unroll
    for (int r = 0; r < 4; ++r) {
        float w16[16];
        #pragma unroll
        for (int mf = 0; mf < 16; ++mf) w16[mf] = acc[mf][r];
        float lm = max16v(w16);
        float gm = gmax16(lm);
        rmx[r] = gm;
        for (int it = 1; it < kk; ++it) {
            unsigned long long bal = __ballot(lm == gm);
            unsigned gmask = (unsigned)((bal >> (g * 16)) & 0xFFFFull);
            int leader = __builtin_ctz(gmask);
            bool skip = (c16 != leader);
            #pragma unroll
            for (int mf = 0; mf < 16; ++mf) {
                bool hit = (!skip) && (w16[mf] == gm);
                w16[mf] = hit ? -INFINITY : w16[mf];
                skip = skip || hit;
            }
            lm = max16v(w16);
            gm = gmax16(lm);
        }
        thr[r] = gm;
    }

    // ---- softmax (in regs) -> P [64][256] @0 ----
    #pragma unroll
    for (int mf = 0; mf < 16; ++mf) {
        #pragma unroll
        for (int r = 0; r < 4; ++r) {
            float a = acc[mf][r];
            acc[mf][r] = (a >= thr[r]) ? __expf(a - rmx[r]) : 0.f;
        }
    }
    float inv_[4];
    #pragma unroll
    for (int r = 0; r < 4; ++r) {
        float s = ((acc[0][r] + acc[1][r]) + (acc[2][r] + acc[3][r]))
                + ((acc[4][r] + acc[5][r]) + (acc[6][r] + acc[7][r]))
                + ((acc[8][r] + acc[9][r]) + (acc[10][r] + acc[11][r]))
                + ((acc[12][r] + acc[13][r]) + (acc[14][r] + acc[15][r]));
        s = gsum16(s);
        inv_[r] = 1.0f / s;
    }
    #pragma unroll
    for (int mf = 0; mf < 16; ++mf) {
        #pragma unroll
        for (int r = 0; r < 4; ++r) {
            int row = w * 16 + g * 4 + r;
            int m2  = (mf * 16 + c16) * 2;
            int off = row * 512 + (m2 ^ ((row & 7) << 4));
            *(unsigned short*)(smem + off) = f2bf(acc[mf][r] * inv_[r]);
        }
    }

    // ---- PV in two 128-m halves; V-half [64d][128m] @32768 ----
    f32x4 o[4];
    #pragma unroll
    for (int df = 0; df < 4; ++df) o[df] = f32x4{0.f, 0.f, 0.f, 0.f};

    #pragma unroll
    for (int half = 0; half < 2; ++half) {
        if (half) __syncthreads();              // prev half V reads done
        #pragma unroll
        for (int it = 0; it < 4; ++it) {
            int idx = t + it * 256;             // 0..1023
            int d = idx >> 4, mc8 = idx & 15;
            ushort8_t val = *(const ushort8_t*)
                &vb[planeV + (size_t)(d * HH + h) * MMM + half * 128 + mc8 * 8];
            int off = 32768 + d * 256 + ((mc8 * 16) ^ ((d & 7) << 4));
            *(ushort8_t*)(smem + off) = val;
        }
        __syncthreads();

        short8 pa[4];
        #pragma unroll
        for (int ks = 0; ks < 4; ++ks) {
            int row = w * 16 + c16;
            int off = row * 512 + ((half * 256 + ks * 64 + g * 16) ^ ((row & 7) << 4));
            pa[ks] = *(const short8*)(smem + off);
        }
        #pragma unroll
        for (int df = 0; df < 4; ++df) {
            int d = df * 16 + c16;
            f32x4 o_ = o[df];
            #pragma unroll
            for (int ks = 0; ks < 4; ++ks) {
                int off = 32768 + d * 256 + ((ks * 64 + g * 16) ^ ((d & 7) << 4));
                short8 vv = *(const short8*)(smem + off);
                o_ = __builtin_amdgcn_mfma_f32_16x16x32_bf16(pa[ks], vv, o_, 0, 0, 0);
            }
            o[df] = o_;
        }
    }
    __syncthreads();        // all P/V reads done; out region free

    // ---- out: frags -> [64d][64n] @0 -> global [channel][n] ----
    #pragma unroll
    for (int df = 0; df < 4; ++df)
        #pragma unroll
        for (int r = 0; r < 4; ++r) {
            int d  = df * 16 + c16;
            int nl = w * 16 + g * 4 + r;
            int off = d * 128 + ((nl * 2) ^ ((d & 7) << 4));
            *(unsigned short*)(smem + off) = f2bf(o[df][r]);
        }
    __syncthreads();
    #pragma unroll
    for (int it = 0; it < 2; ++it) {
        int idx = t + it * 256;                 // 0..511
        int d = idx >> 3, ch = idx & 7;
        int off = d * 128 + ((ch * 16) ^ ((d & 7) << 4));
        ushort8_t val = *(const ushort8_t*)(smem + off);
        *(ushort8_t*)&ob[planeV + (size_t)(d * HH + h) * NNN + n0 + ch * 8] = val;
    }
}

// ---------------------------------------------------------------------------
extern "C" void kernel_launch(void* const* d_in, const int* in_sizes, int n_in,
                              void* d_out, int out_size, void* d_ws, size_t ws_size,
                              hipStream_t stream) {
    const float* x   = (const float*)d_in[0];
    const float* src = (const float*)d_in[1];
    const float* Wq  = (const float*)d_in[2];
    const float* bq  = (const float*)d_in[3];
    const float* Wk  = (const float*)d_in[4];
    const float* bk  = (const float*)d_in[5];
    const float* Wv  = (const float*)d_in[6];
    const float* bv  = (const float*)d_in[7];
    const float* Wm  = (const float*)d_in[8];
    const float* bm  = (const float*)d_in[9];
    const int*   kp  = (const int*)d_in[10];
    float* out = (float*)d_out;

    const size_t F32PLANE  = (size_t)BB * DDIM * NNN * sizeof(float);
    const size_t BF16PLANE = F32PLANE / 2;
    char* ws = (char*)d_ws;
    float* qf = (float*)(ws);
    float* kf = (float*)(ws + F32PLANE);
    bf16*  vb = (bf16*)(ws + 2 * F32PLANE);
    bf16*  ob = (bf16*)(ws + 2 * F32PLANE + BF16PLANE);

    hipFuncSetAttribute((const void*)(projm_kernel<float, bf16>),
                        hipFuncAttributeMaxDynamicSharedMemorySize, 65536);
    hipFuncSetAttribute((const void*)(projm_kernel<bf16, float>),
                        hipFuncAttributeMaxDynamicSharedMemorySize, 65536);
    hipFuncSetAttribute((const void*)attn3_kernel,
                        hipFuncAttributeMaxDynamicSharedMemorySize, 49152);

    // Q, K: f32 projection, bit-identical accumulation to verified path
    dim3 fgrid(NNN / 128, DDIM / 64, BB);   // (2,4,128)
    hipLaunchKernelGGL(proj_kernel, fgrid, dim3(256), 0, stream, x,   Wq, bq, qf);
    hipLaunchKernelGGL(proj_kernel, fgrid, dim3(256), 0, stream, src, Wk, bk, kf);

    // V: MFMA projection (value path)
    dim3 mgrid(2, 2, BB);
    hipLaunchKernelGGL((projm_kernel<float, bf16>), mgrid, dim3(512), 65536, stream,
                       src, Wv, bv, vb);

    hipLaunchKernelGGL(attn3_kernel, dim3(2048), dim3(256), 49152, stream,
                       qf, kf, vb, ob, kp);

    // Output: MFMA projection (value path)
    hipLaunchKernelGGL((projm_kernel<bf16, float>), mgrid, dim3(512), 65536, stream,
                       ob, Wm, bm, out);
}